// Round 10
// baseline (117.637 us; speedup 1.0000x reference)
//
#include <hip/hip_runtime.h>
#include <hip/hip_bf16.h>

#define Bq 4
#define Nn 512
#define Dd 512
#define Hh 8
#define DKk 64

typedef __bf16 bf16x8 __attribute__((ext_vector_type(8)));
typedef __fp16 h16x2 __attribute__((ext_vector_type(2)));
typedef float f32x4 __attribute__((ext_vector_type(4)));
typedef unsigned short u16x8 __attribute__((ext_vector_type(8)));

// fp32 -> bf16 RNE (no NaN inputs here)
static __device__ __forceinline__ unsigned short f2bf(float f) {
    unsigned int u = __float_as_uint(f);
    return (unsigned short)((u + 0x7FFFu + ((u >> 16) & 1u)) >> 16);
}
static __device__ __forceinline__ unsigned short f2h(float f) {
    union { _Float16 h; unsigned short u; } cv;
    cv.h = (_Float16)f;
    return cv.u;
}
static __device__ __forceinline__ float h2f(unsigned short us) {
    union { _Float16 h; unsigned short u; } cv;
    cv.u = us;
    return (float)cv.h;
}
static __device__ __forceinline__ h16x2 u2h2(unsigned int u) {
    union { unsigned int u; h16x2 h; } cv;
    cv.u = u;
    return cv.h;
}
// acc += sc.x*w.x + sc.y*w.y   (v_dot2_f32_f16: 2 MACs / instr, full rate)
static __device__ __forceinline__ float dot2acc(h16x2 sc, unsigned int w, float acc) {
#if __has_builtin(__builtin_amdgcn_fdot2)
    return __builtin_amdgcn_fdot2(sc, u2h2(w), acc, false);
#else
    const h16x2 wh = u2h2(w);
    return fmaf((float)sc.x, (float)wh.x, fmaf((float)sc.y, (float)wh.y, acc));
#endif
}

// ---------------------------------------------------------------------------
// Merged kernel: geo (4096 blocks) + QKV GEMM (768 blocks), striped 16:3 per
// 19-block group (round-5 structure & access patterns — proven 51 us).
// geo inner dot uses v_dot2_f32_f16: (sin,cos) packed per freq via
// v_cvt_pkrtz, weights pre-packed (Ws,Wc) half2 in 1 KB LDS -> 8 dot2 + 2
// ds_read_b128 per (p,f) vs 16 fma + 4 ds_read_b128. Halves both dominant
// issue streams; trans work unchanged (irreducible).
// gemm: bf16 MFMA, W fp32 column-loaded, LDS stride 44. Q pre-scaled 1/8.
// ---------------------------------------------------------------------------
struct PreArgs {
    const float* A[3];
    const float* W[3];
    const float* bias[3];
    unsigned short* C[3];
    int ns[3], cs[3];
    float scale[3];
    const float* box;
    const int* mask;
    const float* Wg;
    const float* bg;
    unsigned short* lw;   // fp16 [B,H,N,N]
};

__global__ __launch_bounds__(256) void pre_k(PreArgs pa)
{
    // pool: geo  -> wpkS u32 [32][8] (1024 B) + bgS f32[8]
    //       gemm -> ABlds u16 [2][64][44] (11264 B)
    __shared__ __align__(16) char pool[11264];
    const int t = threadIdx.x;
    const int r_ = (int)(blockIdx.x % 19), g_ = (int)(blockIdx.x / 19);
    const int l = t & 63, wq = t >> 6;
    const int lrow = l & 15, lgrp = l >> 4;

    if (r_ < 16) {
        // ------------------------- geo (dot2) -------------------------
        unsigned int* wpkS = (unsigned int*)pool;       // [g=32][h=8] half2(Ws,Wc)
        float* bgS = (float*)(pool + 1024);
        {
            const int g = t >> 3, hh = t & 7;           // t covers 32x8 exactly
            union { h16x2 h; unsigned int u; } cv;
            cv.h.x = (__fp16)pa.Wg[(size_t)g * Hh + hh];
            cv.h.y = (__fp16)pa.Wg[(size_t)(32 + g) * Hh + hh];
            wpkS[t] = cv.u;
            if (t < 8) bgS[t] = pa.bg[t];
        }
        __syncthreads();

        const int gb = g_ * 16 + r_;
        const size_t gid = (size_t)gb * 256 + t;
        const int j = (int)(gid & (Nn - 1));
        const int i = (int)((gid >> 9) & (Nn - 1));
        const int b = (int)(gid >> 18);

        const float4 bi = *(const float4*)(pa.box + ((size_t)b * Nn + i) * 4);
        const float4 bj = *(const float4*)(pa.box + ((size_t)b * Nn + j) * 4);
        const float cxi = (bi.x + bi.y) * 0.5f, cyi = (bi.z + bi.w) * 0.5f;
        const float wi = bi.y - bi.x + 1.0f, hi = bi.w - bi.z + 1.0f;
        const float cxj = (bj.x + bj.y) * 0.5f, cyj = (bj.z + bj.w) * 0.5f;
        const float wj = bj.y - bj.x + 1.0f, hj = bj.w - bj.z + 1.0f;

        const float pos0 = __logf(fmaxf(fabsf((cxi - cxj) / wi), 1e-3f));
        const float pos1 = __logf(fmaxf(fabsf((cyi - cyj) / hi), 1e-3f));
        const float pos2 = __logf(wi / wj);
        const float pos3 = __logf(hi / hj);

        const float dimr[8] = {1.0f, 0.421696503f, 0.177827941f, 0.0749894209f,
                               0.0316227766f, 0.0133352143f, 0.00562341325f, 0.00237137371f};

        float acc[8] = {0.f, 0.f, 0.f, 0.f, 0.f, 0.f, 0.f, 0.f};
#pragma unroll 1
        for (int p = 0; p < 4; ++p) {
            const float base = 100.0f * ((p == 0) ? pos0 : (p == 1) ? pos1 : (p == 2) ? pos2 : pos3);
            const unsigned int* wrow = wpkS + (p << 6);   // packs for g = p*8 .. p*8+7
#pragma unroll
            for (int f = 0; f < 8; ++f) {
                float s, c;
                __sincosf(base * dimr[f], &s, &c);
                const h16x2 sc = __builtin_amdgcn_cvt_pkrtz(s, c);
                const uint4 wa = *(const uint4*)(wrow + (f << 3));
                const uint4 wb = *(const uint4*)(wrow + (f << 3) + 4);
                acc[0] = dot2acc(sc, wa.x, acc[0]);
                acc[1] = dot2acc(sc, wa.y, acc[1]);
                acc[2] = dot2acc(sc, wa.z, acc[2]);
                acc[3] = dot2acc(sc, wa.w, acc[3]);
                acc[4] = dot2acc(sc, wb.x, acc[4]);
                acc[5] = dot2acc(sc, wb.y, acc[5]);
                acc[6] = dot2acc(sc, wb.z, acc[6]);
                acc[7] = dot2acc(sc, wb.w, acc[7]);
            }
        }

        const int mk = pa.mask[gid];
        const size_t ob_ = (size_t)b * Hh * Nn * Nn + (size_t)i * Nn + j;
#pragma unroll
        for (int hh = 0; hh < 8; ++hh) {
            const float gw = acc[hh] + bgS[hh];
            const float lwv = (mk == 0) ? -60000.0f : __logf(fmaxf(gw, 1e-6f));
            pa.lw[ob_ + (size_t)hh * Nn * Nn] = f2h(lwv);
        }
    } else {
        // ------------------------- qkv gemm -------------------------
        unsigned short (*ABlds)[64][44] = (unsigned short(*)[64][44])pool;
        const int qid = g_ * 3 + (r_ - 16);
        const int z = qid % 3, tid = qid / 3;
        const int col0 = (tid & 7) << 6, row0 = (tid >> 3) << 6;
        const float* __restrict__ A = pa.A[z];
        const float* __restrict__ W = pa.W[z];

        const int lr = t >> 2, lc8 = (t & 3) << 3;
        const int bn = t & 63, bk8 = (t >> 6) << 3;

        f32x4 acc[4];
#pragma unroll
        for (int nf = 0; nf < 4; ++nf) acc[nf] = (f32x4){0.f, 0.f, 0.f, 0.f};

        for (int k0 = 0; k0 < Dd; k0 += 32) {
            const float* Ap = A + (size_t)(row0 + lr) * Dd + k0 + lc8;
            const float4 f1 = *(const float4*)Ap;
            const float4 f2 = *(const float4*)(Ap + 4);
            u16x8 a8;
            a8[0] = f2bf(f1.x); a8[1] = f2bf(f1.y); a8[2] = f2bf(f1.z); a8[3] = f2bf(f1.w);
            a8[4] = f2bf(f2.x); a8[5] = f2bf(f2.y); a8[6] = f2bf(f2.z); a8[7] = f2bf(f2.w);
            u16x8 b8;
#pragma unroll
            for (int jj = 0; jj < 8; ++jj)
                b8[jj] = f2bf(W[(size_t)(k0 + bk8 + jj) * Dd + col0 + bn]);
            __syncthreads();
            *(u16x8*)&ABlds[0][lr][lc8] = a8;
            *(u16x8*)&ABlds[1][bn][bk8] = b8;
            __syncthreads();
            const bf16x8 a = *(const bf16x8*)&ABlds[0][wq * 16 + lrow][lgrp << 3];
#pragma unroll
            for (int nf = 0; nf < 4; ++nf) {
                const bf16x8 bfr = *(const bf16x8*)&ABlds[1][nf * 16 + lrow][lgrp << 3];
                acc[nf] = __builtin_amdgcn_mfma_f32_16x16x32_bf16(a, bfr, acc[nf], 0, 0, 0);
            }
        }

        const float* bias = pa.bias[z];
        const float scl = pa.scale[z];
        const int ns = pa.ns[z], cs = pa.cs[z];
        const int rbase = row0 + wq * 16 + (lgrp << 2);
#pragma unroll
        for (int nf = 0; nf < 4; ++nf) {
            const int colg = col0 + nf * 16 + lrow;
            const float bv = bias[colg];
#pragma unroll
            for (int r = 0; r < 4; ++r) {
                const int rowg = rbase + r;
                const size_t addr = (size_t)(rowg >> 9) * ((size_t)Nn * Dd)
                                  + (size_t)(rowg & (Nn - 1)) * ns + (size_t)colg * cs;
                pa.C[z][addr] = f2bf((acc[nf][r] + bv) * scl);
            }
        }
    }
}

// ---------------------------------------------------------------------------
// Fused flash attention, bf16 MFMA. Block = (b, h, 64 q-rows), 4 waves.
// K/V/logw register-prefetched one chunk ahead; logw LDS-staged fp16.
// Q pre-scaled by 1/8. (unchanged)
// ---------------------------------------------------------------------------
__global__ __launch_bounds__(256) void attn_k(
    const unsigned short* __restrict__ qb, const unsigned short* __restrict__ kb,
    const unsigned short* __restrict__ vt, const unsigned short* __restrict__ lwh,
    unsigned short* __restrict__ ob)
{
    __shared__ unsigned short Qlds[64][72];
    __shared__ unsigned short Klds[64][72];
    __shared__ unsigned short Vlds[64][72];
    __shared__ unsigned short Plds[4][16][72];
    __shared__ unsigned short LWs[64][72];

    const int t = threadIdx.x;
    const int l = t & 63, wq = t >> 6;
    const int bx = blockIdx.x;
    const int qt = bx & 7, h = (bx >> 3) & 7, b = bx >> 6;
    const int q0 = qt << 6;
    const int sr = t >> 3, sc8 = (t & 7) << 3;
    const int lrow = l & 15, lgrp = l >> 4;
    const int qr0 = t >> 3, c80 = (t & 7) << 3;
    const int qr1 = 32 + (t >> 3), c81 = c80;

    const size_t lwb = ((size_t)(b * Hh + h) * Nn + q0) * Nn;

#pragma unroll
    for (int it = 0; it < 2; ++it) {
        const int r = it * 32 + sr;
        *(u16x8*)&Qlds[r][sc8] =
            *(const u16x8*)(qb + (((size_t)b * Nn + q0 + r) * Hh + h) * DKk + sc8);
    }

    u16x8 kr[2], vr[2], lwr[2];
#pragma unroll
    for (int it = 0; it < 2; ++it) {
        const int r = it * 32 + sr;
        kr[it] = *(const u16x8*)(kb + (((size_t)b * Nn + r) * Hh + h) * DKk + sc8);
        vr[it] = *(const u16x8*)(vt + ((size_t)(b * Hh + h) * DKk + r) * Nn + sc8);
    }
    lwr[0] = *(const u16x8*)(lwh + lwb + (size_t)qr0 * Nn + c80);
    lwr[1] = *(const u16x8*)(lwh + lwb + (size_t)qr1 * Nn + c81);
#pragma unroll
    for (int it = 0; it < 2; ++it) {
        const int r = it * 32 + sr;
        *(u16x8*)&Klds[r][sc8] = kr[it];
        *(u16x8*)&Vlds[r][sc8] = vr[it];
    }
    *(u16x8*)&LWs[qr0][c80] = lwr[0];
    *(u16x8*)&LWs[qr1][c81] = lwr[1];
    __syncthreads();

    bf16x8 qa[2];
    qa[0] = *(const bf16x8*)&Qlds[wq * 16 + lrow][lgrp << 3];
    qa[1] = *(const bf16x8*)&Qlds[wq * 16 + lrow][32 + (lgrp << 3)];

    float m[4], lsum[4];
    f32x4 oacc[4];
#pragma unroll
    for (int r = 0; r < 4; ++r) { m[r] = -1e30f; lsum[r] = 0.f; }
#pragma unroll
    for (int fd = 0; fd < 4; ++fd) oacc[fd] = (f32x4){0.f, 0.f, 0.f, 0.f};

    for (int c = 0; c < 8; ++c) {
        if (c) __syncthreads();
        if (c < 7) {
            const int k1 = (c + 1) << 6;
#pragma unroll
            for (int it = 0; it < 2; ++it) {
                const int r = it * 32 + sr;
                kr[it] = *(const u16x8*)(kb + (((size_t)b * Nn + k1 + r) * Hh + h) * DKk + sc8);
                vr[it] = *(const u16x8*)(vt + ((size_t)(b * Hh + h) * DKk + r) * Nn + k1 + sc8);
            }
            lwr[0] = *(const u16x8*)(lwh + lwb + (size_t)qr0 * Nn + k1 + c80);
            lwr[1] = *(const u16x8*)(lwh + lwb + (size_t)qr1 * Nn + k1 + c81);
        }

        f32x4 sacc[4];
#pragma unroll
        for (int f = 0; f < 4; ++f) sacc[f] = (f32x4){0.f, 0.f, 0.f, 0.f};
#pragma unroll
        for (int ks = 0; ks < 2; ++ks)
#pragma unroll
            for (int f = 0; f < 4; ++f) {
                const bf16x8 kf = *(const bf16x8*)&Klds[f * 16 + lrow][(ks << 5) + (lgrp << 3)];
                sacc[f] = __builtin_amdgcn_mfma_f32_16x16x32_bf16(qa[ks], kf, sacc[f], 0, 0, 0);
            }

        float p[4][4], mx[4];
#pragma unroll
        for (int r = 0; r < 4; ++r) mx[r] = -1e30f;
#pragma unroll
        for (int f = 0; f < 4; ++f) {
#pragma unroll
            for (int r = 0; r < 4; ++r) {
                const float lg = sacc[f][r] + h2f(LWs[wq * 16 + lgrp * 4 + r][f * 16 + lrow]);
                p[f][r] = lg;
                mx[r] = fmaxf(mx[r], lg);
            }
        }
#pragma unroll
        for (int r = 0; r < 4; ++r) {
            float cm = mx[r];
            cm = fmaxf(cm, __shfl_xor(cm, 1));
            cm = fmaxf(cm, __shfl_xor(cm, 2));
            cm = fmaxf(cm, __shfl_xor(cm, 4));
            cm = fmaxf(cm, __shfl_xor(cm, 8));
            const float mn = fmaxf(m[r], cm);
            const float sc = __expf(m[r] - mn);
            m[r] = mn;
            float ps = 0.f;
#pragma unroll
            for (int f = 0; f < 4; ++f) {
                p[f][r] = __expf(p[f][r] - mn);
                ps += p[f][r];
            }
            ps += __shfl_xor(ps, 1);
            ps += __shfl_xor(ps, 2);
            ps += __shfl_xor(ps, 4);
            ps += __shfl_xor(ps, 8);
            lsum[r] = lsum[r] * sc + ps;
#pragma unroll
            for (int fd = 0; fd < 4; ++fd) oacc[fd][r] *= sc;
        }

#pragma unroll
        for (int f = 0; f < 4; ++f)
#pragma unroll
            for (int r = 0; r < 4; ++r)
                Plds[wq][lgrp * 4 + r][f * 16 + lrow] = f2bf(p[f][r]);

#pragma unroll
        for (int ks = 0; ks < 2; ++ks) {
            const bf16x8 pafr = *(const bf16x8*)&Plds[wq][lrow][(ks << 5) + (lgrp << 3)];
#pragma unroll
            for (int fd = 0; fd < 4; ++fd) {
                const bf16x8 vf = *(const bf16x8*)&Vlds[fd * 16 + lrow][(ks << 5) + (lgrp << 3)];
                oacc[fd] = __builtin_amdgcn_mfma_f32_16x16x32_bf16(pafr, vf, oacc[fd], 0, 0, 0);
            }
        }

        if (c < 7) {
            __syncthreads();
#pragma unroll
            for (int it = 0; it < 2; ++it) {
                const int r = it * 32 + sr;
                *(u16x8*)&Klds[r][sc8] = kr[it];
                *(u16x8*)&Vlds[r][sc8] = vr[it];
            }
            *(u16x8*)&LWs[qr0][c80] = lwr[0];
            *(u16x8*)&LWs[qr1][c81] = lwr[1];
        }
    }

#pragma unroll
    for (int r = 0; r < 4; ++r) {
        const float inv = 1.0f / lsum[r];
        const int qrow = q0 + wq * 16 + lgrp * 4 + r;
#pragma unroll
        for (int fd = 0; fd < 4; ++fd) {
            ob[(((size_t)b * Nn + qrow) * Hh + h) * DKk + fd * 16 + lrow] =
                f2bf(oacc[fd][r] * inv);
        }
    }
}

// ---------------------------------------------------------------------------
// Output projection: C[2048,512] fp32 = A(bf16) @ Wo(fp32, column-loaded) + bo
// LDS stride 44 (conflict-fixed).
// ---------------------------------------------------------------------------
__global__ __launch_bounds__(256) void outproj_k(
    const unsigned short* __restrict__ A, const float* __restrict__ W,
    const float* __restrict__ bias, float* __restrict__ C)
{
    __shared__ unsigned short Alds[64][44];
    __shared__ unsigned short Blds[64][44];
    const int t = threadIdx.x;
    const int l = t & 63, wq = t >> 6;
    const int col0 = (int)(blockIdx.x) << 6, row0 = (int)(blockIdx.y) << 6;
    const int lr = t >> 2, lc8 = (t & 3) << 3;
    const int bn = t & 63, bk8 = (t >> 6) << 3;
    const int lrow = l & 15, lgrp = l >> 4;

    f32x4 acc[4];
#pragma unroll
    for (int nf = 0; nf < 4; ++nf) acc[nf] = (f32x4){0.f, 0.f, 0.f, 0.f};

    for (int k0 = 0; k0 < Dd; k0 += 32) {
        const u16x8 a8 = *(const u16x8*)(A + (size_t)(row0 + lr) * Dd + k0 + lc8);
        u16x8 b8;
#pragma unroll
        for (int jj = 0; jj < 8; ++jj)
            b8[jj] = f2bf(W[(size_t)(k0 + bk8 + jj) * Dd + col0 + bn]);
        __syncthreads();
        *(u16x8*)&Alds[lr][lc8] = a8;
        *(u16x8*)&Blds[bn][bk8] = b8;
        __syncthreads();
        const bf16x8 a = *(const bf16x8*)&Alds[wq * 16 + lrow][lgrp << 3];
#pragma unroll
        for (int nf = 0; nf < 4; ++nf) {
            const bf16x8 bfr = *(const bf16x8*)&Blds[nf * 16 + lrow][lgrp << 3];
            acc[nf] = __builtin_amdgcn_mfma_f32_16x16x32_bf16(a, bfr, acc[nf], 0, 0, 0);
        }
    }

    const int rbase = row0 + wq * 16 + (lgrp << 2);
#pragma unroll
    for (int nf = 0; nf < 4; ++nf) {
        const int colg = col0 + nf * 16 + lrow;
        const float bv = bias[colg];
#pragma unroll
        for (int r = 0; r < 4; ++r)
            C[(size_t)(rbase + r) * Dd + colg] = acc[nf][r] + bv;
    }
}

// ---------------------------------------------------------------------------
extern "C" void kernel_launch(void* const* d_in, const int* in_sizes, int n_in,
                              void* d_out, int out_size, void* d_ws, size_t ws_size,
                              hipStream_t stream)
{
    (void)in_sizes; (void)n_in; (void)out_size; (void)ws_size;

    const float* q_in = (const float*)d_in[0];
    const float* k_in = (const float*)d_in[1];
    const float* v_in = (const float*)d_in[2];
    const float* box  = (const float*)d_in[3];
    const int*   mask = (const int*)d_in[4];
    const float* Wq = (const float*)d_in[5];
    const float* bq = (const float*)d_in[6];
    const float* Wk = (const float*)d_in[7];
    const float* bk = (const float*)d_in[8];
    const float* Wv = (const float*)d_in[9];
    const float* bv = (const float*)d_in[10];
    const float* Wo = (const float*)d_in[11];
    const float* bo = (const float*)d_in[12];
    const float* Wg = (const float*)d_in[13];
    const float* bg = (const float*)d_in[14];
    float* out = (float*)d_out;

    char* ws = (char*)d_ws;
    unsigned short* qb  = (unsigned short*)(ws);                 // 2 MB  [b,n,h,d] bf16 (pre-scaled 1/8)
    unsigned short* kb  = (unsigned short*)(ws + (2u << 20));    // 2 MB  [b,n,h,d] bf16
    unsigned short* vt  = (unsigned short*)(ws + (4u << 20));    // 2 MB  [b,h,d,n] bf16
    unsigned short* ob  = (unsigned short*)(ws + (6u << 20));    // 2 MB  [b,n,h,d] bf16
    unsigned short* lwh = (unsigned short*)(ws + (8u << 20));    // 16 MB [b,h,i,j] fp16

    // 1) merged geo(dot2) + QKV projections, striped 16:3 per 19 blocks
    PreArgs pa;
    pa.A[0] = q_in; pa.A[1] = k_in; pa.A[2] = v_in;
    pa.W[0] = Wq;   pa.W[1] = Wk;   pa.W[2] = Wv;
    pa.bias[0] = bq; pa.bias[1] = bk; pa.bias[2] = bv;
    pa.C[0] = qb; pa.C[1] = kb; pa.C[2] = vt;
    pa.ns[0] = Dd; pa.ns[1] = Dd; pa.ns[2] = 1;
    pa.cs[0] = 1;  pa.cs[1] = 1;  pa.cs[2] = Nn;
    pa.scale[0] = 0.125f; pa.scale[1] = 1.0f; pa.scale[2] = 1.0f;
    pa.box = box; pa.mask = mask; pa.Wg = Wg; pa.bg = bg; pa.lw = lwh;
    pre_k<<<dim3(4864), 256, 0, stream>>>(pa);

    // 2) fused attention
    attn_k<<<dim3(Bq * Hh * (Nn / 64)), 256, 0, stream>>>(qb, kb, vt, lwh, ob);

    // 3) output projection
    outproj_k<<<dim3(8, 32), 256, 0, stream>>>(ob, Wo, bo, out);
}

// Round 11
// 107.627 us; speedup vs baseline: 1.0930x; 1.0930x over previous
//
#include <hip/hip_runtime.h>
#include <hip/hip_bf16.h>

#define Bq 4
#define Nn 512
#define Dd 512
#define Hh 8
#define DKk 64

typedef __bf16 bf16x8 __attribute__((ext_vector_type(8)));
typedef float f32x4 __attribute__((ext_vector_type(4)));
typedef unsigned short u16x8 __attribute__((ext_vector_type(8)));

// fp32 -> bf16 RNE (no NaN inputs here)
static __device__ __forceinline__ unsigned short f2bf(float f) {
    unsigned int u = __float_as_uint(f);
    return (unsigned short)((u + 0x7FFFu + ((u >> 16) & 1u)) >> 16);
}
static __device__ __forceinline__ unsigned short f2h(float f) {
    union { _Float16 h; unsigned short u; } cv;
    cv.h = (_Float16)f;
    return cv.u;
}
static __device__ __forceinline__ float h2f(unsigned short us) {
    union { _Float16 h; unsigned short u; } cv;
    cv.u = us;
    return (float)cv.h;
}

// ---------------------------------------------------------------------------
// Merged kernel: geo (2048 blocks, 2 pairs/thread) + QKV GEMM (768 blocks),
// striped 8:3 per 11-block group.
// geo: block = (b, i); thread t handles pairs (i, t) and (i, t+256). The 4
// ds_read_b128 weight reads per (p,f) now feed 32 fma (16/pair) -> LDS-read
// stream per pair is halved (round-5 was LDS-throughput bound: 128 reads x
// ~12cyc = 1536 vs 512 fma x 2 = 1024). Interior math identical to round 5.
// gemm: bf16 MFMA, W fp32 column-loaded, LDS stride 44 (0 conflicts, r10).
// Q pre-scaled by 1/8 (exact).
// ---------------------------------------------------------------------------
struct PreArgs {
    const float* A[3];
    const float* W[3];
    const float* bias[3];
    unsigned short* C[3];
    int ns[3], cs[3];
    float scale[3];
    const float* box;
    const int* mask;
    const float* Wg;
    const float* bg;
    unsigned short* lw;   // fp16 [B,H,N,N]
};

__global__ __launch_bounds__(256) void pre_k(PreArgs pa)
{
    // pool: geo  -> WgS f32 [64][8] (2048 B) + bgS f32[8]
    //       gemm -> ABlds u16 [2][64][44] (11264 B)
    __shared__ __align__(16) char pool[11264];
    const int t = threadIdx.x;
    const int r_ = (int)(blockIdx.x % 11), g_ = (int)(blockIdx.x / 11);
    const int l = t & 63, wq = t >> 6;
    const int lrow = l & 15, lgrp = l >> 4;

    if (r_ < 8) {
        // ------------------------- geo (2 pairs / thread) ------------------
        float (*WgS)[8] = (float(*)[8])pool;
        float* bgS = (float*)(pool + 2048);
        if (t < 128) ((float4*)&WgS[0][0])[t] = ((const float4*)pa.Wg)[t];
        if (t < 8) bgS[t] = pa.bg[t];
        __syncthreads();

        const int gb = g_ * 8 + r_;            // 0..2047 = (b, i)
        const int b = gb >> 9, i = gb & (Nn - 1);
        const int j0 = t, j1 = t + 256;

        const float4 bi = *(const float4*)(pa.box + (size_t)gb * 4);
        const float4 bj0 = *(const float4*)(pa.box + ((size_t)b * Nn + j0) * 4);
        const float4 bj1 = *(const float4*)(pa.box + ((size_t)b * Nn + j1) * 4);

        const float cxi = (bi.x + bi.y) * 0.5f, cyi = (bi.z + bi.w) * 0.5f;
        const float wi = bi.y - bi.x + 1.0f, hi = bi.w - bi.z + 1.0f;

        const float cxj0 = (bj0.x + bj0.y) * 0.5f, cyj0 = (bj0.z + bj0.w) * 0.5f;
        const float wj0 = bj0.y - bj0.x + 1.0f, hj0 = bj0.w - bj0.z + 1.0f;
        const float cxj1 = (bj1.x + bj1.y) * 0.5f, cyj1 = (bj1.z + bj1.w) * 0.5f;
        const float wj1 = bj1.y - bj1.x + 1.0f, hj1 = bj1.w - bj1.z + 1.0f;

        const float a00 = __logf(fmaxf(fabsf((cxi - cxj0) / wi), 1e-3f));
        const float a01 = __logf(fmaxf(fabsf((cyi - cyj0) / hi), 1e-3f));
        const float a02 = __logf(wi / wj0);
        const float a03 = __logf(hi / hj0);
        const float a10 = __logf(fmaxf(fabsf((cxi - cxj1) / wi), 1e-3f));
        const float a11 = __logf(fmaxf(fabsf((cyi - cyj1) / hi), 1e-3f));
        const float a12 = __logf(wi / wj1);
        const float a13 = __logf(hi / hj1);

        const float dimr[8] = {1.0f, 0.421696503f, 0.177827941f, 0.0749894209f,
                               0.0316227766f, 0.0133352143f, 0.00562341325f, 0.00237137371f};

        float acc0[8] = {0.f, 0.f, 0.f, 0.f, 0.f, 0.f, 0.f, 0.f};
        float acc1[8] = {0.f, 0.f, 0.f, 0.f, 0.f, 0.f, 0.f, 0.f};
#pragma unroll 1
        for (int p = 0; p < 4; ++p) {
            const float b0 = 100.0f * ((p == 0) ? a00 : (p == 1) ? a01 : (p == 2) ? a02 : a03);
            const float b1 = 100.0f * ((p == 0) ? a10 : (p == 1) ? a11 : (p == 2) ? a12 : a13);
            const int g0 = p << 3;
#pragma unroll
            for (int f = 0; f < 8; ++f) {
                float s0, c0, s1, c1;
                __sincosf(b0 * dimr[f], &s0, &c0);
                __sincosf(b1 * dimr[f], &s1, &c1);
                const int g = g0 + f;
                const float4 wa = *(const float4*)&WgS[g][0];
                const float4 wb = *(const float4*)&WgS[g][4];
                const float4 ca = *(const float4*)&WgS[g + 32][0];
                const float4 cb = *(const float4*)&WgS[g + 32][4];
                acc0[0] = fmaf(s0, wa.x, fmaf(c0, ca.x, acc0[0]));
                acc0[1] = fmaf(s0, wa.y, fmaf(c0, ca.y, acc0[1]));
                acc0[2] = fmaf(s0, wa.z, fmaf(c0, ca.z, acc0[2]));
                acc0[3] = fmaf(s0, wa.w, fmaf(c0, ca.w, acc0[3]));
                acc0[4] = fmaf(s0, wb.x, fmaf(c0, cb.x, acc0[4]));
                acc0[5] = fmaf(s0, wb.y, fmaf(c0, cb.y, acc0[5]));
                acc0[6] = fmaf(s0, wb.z, fmaf(c0, cb.z, acc0[6]));
                acc0[7] = fmaf(s0, wb.w, fmaf(c0, cb.w, acc0[7]));
                acc1[0] = fmaf(s1, wa.x, fmaf(c1, ca.x, acc1[0]));
                acc1[1] = fmaf(s1, wa.y, fmaf(c1, ca.y, acc1[1]));
                acc1[2] = fmaf(s1, wa.z, fmaf(c1, ca.z, acc1[2]));
                acc1[3] = fmaf(s1, wa.w, fmaf(c1, ca.w, acc1[3]));
                acc1[4] = fmaf(s1, wb.x, fmaf(c1, cb.x, acc1[4]));
                acc1[5] = fmaf(s1, wb.y, fmaf(c1, cb.y, acc1[5]));
                acc1[6] = fmaf(s1, wb.z, fmaf(c1, cb.z, acc1[6]));
                acc1[7] = fmaf(s1, wb.w, fmaf(c1, cb.w, acc1[7]));
            }
        }

        const size_t mbase = (size_t)gb * Nn;
        const int mk0 = pa.mask[mbase + j0];
        const int mk1 = pa.mask[mbase + j1];
        const size_t ob_ = (size_t)b * Hh * Nn * Nn + (size_t)i * Nn;
#pragma unroll
        for (int hh = 0; hh < 8; ++hh) {
            const float gw0 = acc0[hh] + bgS[hh];
            const float gw1 = acc1[hh] + bgS[hh];
            const float lw0 = (mk0 == 0) ? -60000.0f : __logf(fmaxf(gw0, 1e-6f));
            const float lw1 = (mk1 == 0) ? -60000.0f : __logf(fmaxf(gw1, 1e-6f));
            pa.lw[ob_ + (size_t)hh * Nn * Nn + j0] = f2h(lw0);
            pa.lw[ob_ + (size_t)hh * Nn * Nn + j1] = f2h(lw1);
        }
    } else {
        // ------------------------- qkv gemm -------------------------
        unsigned short (*ABlds)[64][44] = (unsigned short(*)[64][44])pool;
        const int qid = g_ * 3 + (r_ - 8);
        const int z = qid % 3, tid = qid / 3;
        const int col0 = (tid & 7) << 6, row0 = (tid >> 3) << 6;
        const float* __restrict__ A = pa.A[z];
        const float* __restrict__ W = pa.W[z];

        const int lr = t >> 2, lc8 = (t & 3) << 3;
        const int bn = t & 63, bk8 = (t >> 6) << 3;

        f32x4 acc[4];
#pragma unroll
        for (int nf = 0; nf < 4; ++nf) acc[nf] = (f32x4){0.f, 0.f, 0.f, 0.f};

        for (int k0 = 0; k0 < Dd; k0 += 32) {
            const float* Ap = A + (size_t)(row0 + lr) * Dd + k0 + lc8;
            const float4 f1 = *(const float4*)Ap;
            const float4 f2 = *(const float4*)(Ap + 4);
            u16x8 a8;
            a8[0] = f2bf(f1.x); a8[1] = f2bf(f1.y); a8[2] = f2bf(f1.z); a8[3] = f2bf(f1.w);
            a8[4] = f2bf(f2.x); a8[5] = f2bf(f2.y); a8[6] = f2bf(f2.z); a8[7] = f2bf(f2.w);
            u16x8 b8;
#pragma unroll
            for (int jj = 0; jj < 8; ++jj)
                b8[jj] = f2bf(W[(size_t)(k0 + bk8 + jj) * Dd + col0 + bn]);
            __syncthreads();
            *(u16x8*)&ABlds[0][lr][lc8] = a8;
            *(u16x8*)&ABlds[1][bn][bk8] = b8;
            __syncthreads();
            const bf16x8 a = *(const bf16x8*)&ABlds[0][wq * 16 + lrow][lgrp << 3];
#pragma unroll
            for (int nf = 0; nf < 4; ++nf) {
                const bf16x8 bfr = *(const bf16x8*)&ABlds[1][nf * 16 + lrow][lgrp << 3];
                acc[nf] = __builtin_amdgcn_mfma_f32_16x16x32_bf16(a, bfr, acc[nf], 0, 0, 0);
            }
        }

        const float* bias = pa.bias[z];
        const float scl = pa.scale[z];
        const int ns = pa.ns[z], cs = pa.cs[z];
        const int rbase = row0 + wq * 16 + (lgrp << 2);
#pragma unroll
        for (int nf = 0; nf < 4; ++nf) {
            const int colg = col0 + nf * 16 + lrow;
            const float bv = bias[colg];
#pragma unroll
            for (int r = 0; r < 4; ++r) {
                const int rowg = rbase + r;
                const size_t addr = (size_t)(rowg >> 9) * ((size_t)Nn * Dd)
                                  + (size_t)(rowg & (Nn - 1)) * ns + (size_t)colg * cs;
                pa.C[z][addr] = f2bf((acc[nf][r] + bv) * scl);
            }
        }
    }
}

// ---------------------------------------------------------------------------
// Fused flash attention, bf16 MFMA. Block = (b, h, 64 q-rows), 4 waves.
// K/V/logw register-prefetched one chunk ahead; logw LDS-staged fp16.
// Q pre-scaled by 1/8. (unchanged from round 5)
// ---------------------------------------------------------------------------
__global__ __launch_bounds__(256) void attn_k(
    const unsigned short* __restrict__ qb, const unsigned short* __restrict__ kb,
    const unsigned short* __restrict__ vt, const unsigned short* __restrict__ lwh,
    unsigned short* __restrict__ ob)
{
    __shared__ unsigned short Qlds[64][72];
    __shared__ unsigned short Klds[64][72];
    __shared__ unsigned short Vlds[64][72];
    __shared__ unsigned short Plds[4][16][72];
    __shared__ unsigned short LWs[64][72];

    const int t = threadIdx.x;
    const int l = t & 63, wq = t >> 6;
    const int bx = blockIdx.x;
    const int qt = bx & 7, h = (bx >> 3) & 7, b = bx >> 6;
    const int q0 = qt << 6;
    const int sr = t >> 3, sc8 = (t & 7) << 3;
    const int lrow = l & 15, lgrp = l >> 4;
    const int qr0 = t >> 3, c80 = (t & 7) << 3;
    const int qr1 = 32 + (t >> 3), c81 = c80;

    const size_t lwb = ((size_t)(b * Hh + h) * Nn + q0) * Nn;

#pragma unroll
    for (int it = 0; it < 2; ++it) {
        const int r = it * 32 + sr;
        *(u16x8*)&Qlds[r][sc8] =
            *(const u16x8*)(qb + (((size_t)b * Nn + q0 + r) * Hh + h) * DKk + sc8);
    }

    u16x8 kr[2], vr[2], lwr[2];
#pragma unroll
    for (int it = 0; it < 2; ++it) {
        const int r = it * 32 + sr;
        kr[it] = *(const u16x8*)(kb + (((size_t)b * Nn + r) * Hh + h) * DKk + sc8);
        vr[it] = *(const u16x8*)(vt + ((size_t)(b * Hh + h) * DKk + r) * Nn + sc8);
    }
    lwr[0] = *(const u16x8*)(lwh + lwb + (size_t)qr0 * Nn + c80);
    lwr[1] = *(const u16x8*)(lwh + lwb + (size_t)qr1 * Nn + c81);
#pragma unroll
    for (int it = 0; it < 2; ++it) {
        const int r = it * 32 + sr;
        *(u16x8*)&Klds[r][sc8] = kr[it];
        *(u16x8*)&Vlds[r][sc8] = vr[it];
    }
    *(u16x8*)&LWs[qr0][c80] = lwr[0];
    *(u16x8*)&LWs[qr1][c81] = lwr[1];
    __syncthreads();

    bf16x8 qa[2];
    qa[0] = *(const bf16x8*)&Qlds[wq * 16 + lrow][lgrp << 3];
    qa[1] = *(const bf16x8*)&Qlds[wq * 16 + lrow][32 + (lgrp << 3)];

    float m[4], lsum[4];
    f32x4 oacc[4];
#pragma unroll
    for (int r = 0; r < 4; ++r) { m[r] = -1e30f; lsum[r] = 0.f; }
#pragma unroll
    for (int fd = 0; fd < 4; ++fd) oacc[fd] = (f32x4){0.f, 0.f, 0.f, 0.f};

    for (int c = 0; c < 8; ++c) {
        if (c) __syncthreads();
        if (c < 7) {
            const int k1 = (c + 1) << 6;
#pragma unroll
            for (int it = 0; it < 2; ++it) {
                const int r = it * 32 + sr;
                kr[it] = *(const u16x8*)(kb + (((size_t)b * Nn + k1 + r) * Hh + h) * DKk + sc8);
                vr[it] = *(const u16x8*)(vt + ((size_t)(b * Hh + h) * DKk + r) * Nn + k1 + sc8);
            }
            lwr[0] = *(const u16x8*)(lwh + lwb + (size_t)qr0 * Nn + k1 + c80);
            lwr[1] = *(const u16x8*)(lwh + lwb + (size_t)qr1 * Nn + k1 + c81);
        }

        f32x4 sacc[4];
#pragma unroll
        for (int f = 0; f < 4; ++f) sacc[f] = (f32x4){0.f, 0.f, 0.f, 0.f};
#pragma unroll
        for (int ks = 0; ks < 2; ++ks)
#pragma unroll
            for (int f = 0; f < 4; ++f) {
                const bf16x8 kf = *(const bf16x8*)&Klds[f * 16 + lrow][(ks << 5) + (lgrp << 3)];
                sacc[f] = __builtin_amdgcn_mfma_f32_16x16x32_bf16(qa[ks], kf, sacc[f], 0, 0, 0);
            }

        float p[4][4], mx[4];
#pragma unroll
        for (int r = 0; r < 4; ++r) mx[r] = -1e30f;
#pragma unroll
        for (int f = 0; f < 4; ++f) {
#pragma unroll
            for (int r = 0; r < 4; ++r) {
                const float lg = sacc[f][r] + h2f(LWs[wq * 16 + lgrp * 4 + r][f * 16 + lrow]);
                p[f][r] = lg;
                mx[r] = fmaxf(mx[r], lg);
            }
        }
#pragma unroll
        for (int r = 0; r < 4; ++r) {
            float cm = mx[r];
            cm = fmaxf(cm, __shfl_xor(cm, 1));
            cm = fmaxf(cm, __shfl_xor(cm, 2));
            cm = fmaxf(cm, __shfl_xor(cm, 4));
            cm = fmaxf(cm, __shfl_xor(cm, 8));
            const float mn = fmaxf(m[r], cm);
            const float sc = __expf(m[r] - mn);
            m[r] = mn;
            float ps = 0.f;
#pragma unroll
            for (int f = 0; f < 4; ++f) {
                p[f][r] = __expf(p[f][r] - mn);
                ps += p[f][r];
            }
            ps += __shfl_xor(ps, 1);
            ps += __shfl_xor(ps, 2);
            ps += __shfl_xor(ps, 4);
            ps += __shfl_xor(ps, 8);
            lsum[r] = lsum[r] * sc + ps;
#pragma unroll
            for (int fd = 0; fd < 4; ++fd) oacc[fd][r] *= sc;
        }

#pragma unroll
        for (int f = 0; f < 4; ++f)
#pragma unroll
            for (int r = 0; r < 4; ++r)
                Plds[wq][lgrp * 4 + r][f * 16 + lrow] = f2bf(p[f][r]);

#pragma unroll
        for (int ks = 0; ks < 2; ++ks) {
            const bf16x8 pafr = *(const bf16x8*)&Plds[wq][lrow][(ks << 5) + (lgrp << 3)];
#pragma unroll
            for (int fd = 0; fd < 4; ++fd) {
                const bf16x8 vf = *(const bf16x8*)&Vlds[fd * 16 + lrow][(ks << 5) + (lgrp << 3)];
                oacc[fd] = __builtin_amdgcn_mfma_f32_16x16x32_bf16(pafr, vf, oacc[fd], 0, 0, 0);
            }
        }

        if (c < 7) {
            __syncthreads();
#pragma unroll
            for (int it = 0; it < 2; ++it) {
                const int r = it * 32 + sr;
                *(u16x8*)&Klds[r][sc8] = kr[it];
                *(u16x8*)&Vlds[r][sc8] = vr[it];
            }
            *(u16x8*)&LWs[qr0][c80] = lwr[0];
            *(u16x8*)&LWs[qr1][c81] = lwr[1];
        }
    }

#pragma unroll
    for (int r = 0; r < 4; ++r) {
        const float inv = 1.0f / lsum[r];
        const int qrow = q0 + wq * 16 + lgrp * 4 + r;
#pragma unroll
        for (int fd = 0; fd < 4; ++fd) {
            ob[(((size_t)b * Nn + qrow) * Hh + h) * DKk + fd * 16 + lrow] =
                f2bf(oacc[fd][r] * inv);
        }
    }
}

// ---------------------------------------------------------------------------
// Output projection: C[2048,512] fp32 = A(bf16) @ Wo(fp32, column-loaded) + bo
// LDS stride 44.
// ---------------------------------------------------------------------------
__global__ __launch_bounds__(256) void outproj_k(
    const unsigned short* __restrict__ A, const float* __restrict__ W,
    const float* __restrict__ bias, float* __restrict__ C)
{
    __shared__ unsigned short Alds[64][44];
    __shared__ unsigned short Blds[64][44];
    const int t = threadIdx.x;
    const int l = t & 63, wq = t >> 6;
    const int col0 = (int)(blockIdx.x) << 6, row0 = (int)(blockIdx.y) << 6;
    const int lr = t >> 2, lc8 = (t & 3) << 3;
    const int bn = t & 63, bk8 = (t >> 6) << 3;
    const int lrow = l & 15, lgrp = l >> 4;

    f32x4 acc[4];
#pragma unroll
    for (int nf = 0; nf < 4; ++nf) acc[nf] = (f32x4){0.f, 0.f, 0.f, 0.f};

    for (int k0 = 0; k0 < Dd; k0 += 32) {
        const u16x8 a8 = *(const u16x8*)(A + (size_t)(row0 + lr) * Dd + k0 + lc8);
        u16x8 b8;
#pragma unroll
        for (int jj = 0; jj < 8; ++jj)
            b8[jj] = f2bf(W[(size_t)(k0 + bk8 + jj) * Dd + col0 + bn]);
        __syncthreads();
        *(u16x8*)&Alds[lr][lc8] = a8;
        *(u16x8*)&Blds[bn][bk8] = b8;
        __syncthreads();
        const bf16x8 a = *(const bf16x8*)&Alds[wq * 16 + lrow][lgrp << 3];
#pragma unroll
        for (int nf = 0; nf < 4; ++nf) {
            const bf16x8 bfr = *(const bf16x8*)&Blds[nf * 16 + lrow][lgrp << 3];
            acc[nf] = __builtin_amdgcn_mfma_f32_16x16x32_bf16(a, bfr, acc[nf], 0, 0, 0);
        }
    }

    const int rbase = row0 + wq * 16 + (lgrp << 2);
#pragma unroll
    for (int nf = 0; nf < 4; ++nf) {
        const int colg = col0 + nf * 16 + lrow;
        const float bv = bias[colg];
#pragma unroll
        for (int r = 0; r < 4; ++r)
            C[(size_t)(rbase + r) * Dd + colg] = acc[nf][r] + bv;
    }
}

// ---------------------------------------------------------------------------
extern "C" void kernel_launch(void* const* d_in, const int* in_sizes, int n_in,
                              void* d_out, int out_size, void* d_ws, size_t ws_size,
                              hipStream_t stream)
{
    (void)in_sizes; (void)n_in; (void)out_size; (void)ws_size;

    const float* q_in = (const float*)d_in[0];
    const float* k_in = (const float*)d_in[1];
    const float* v_in = (const float*)d_in[2];
    const float* box  = (const float*)d_in[3];
    const int*   mask = (const int*)d_in[4];
    const float* Wq = (const float*)d_in[5];
    const float* bq = (const float*)d_in[6];
    const float* Wk = (const float*)d_in[7];
    const float* bk = (const float*)d_in[8];
    const float* Wv = (const float*)d_in[9];
    const float* bv = (const float*)d_in[10];
    const float* Wo = (const float*)d_in[11];
    const float* bo = (const float*)d_in[12];
    const float* Wg = (const float*)d_in[13];
    const float* bg = (const float*)d_in[14];
    float* out = (float*)d_out;

    char* ws = (char*)d_ws;
    unsigned short* qb  = (unsigned short*)(ws);                 // 2 MB  [b,n,h,d] bf16 (pre-scaled 1/8)
    unsigned short* kb  = (unsigned short*)(ws + (2u << 20));    // 2 MB  [b,n,h,d] bf16
    unsigned short* vt  = (unsigned short*)(ws + (4u << 20));    // 2 MB  [b,h,d,n] bf16
    unsigned short* ob  = (unsigned short*)(ws + (6u << 20));    // 2 MB  [b,n,h,d] bf16
    unsigned short* lwh = (unsigned short*)(ws + (8u << 20));    // 16 MB [b,h,i,j] fp16

    // 1) merged geo(2-pair) + QKV projections, striped 8:3 per 11 blocks
    PreArgs pa;
    pa.A[0] = q_in; pa.A[1] = k_in; pa.A[2] = v_in;
    pa.W[0] = Wq;   pa.W[1] = Wk;   pa.W[2] = Wv;
    pa.bias[0] = bq; pa.bias[1] = bk; pa.bias[2] = bv;
    pa.C[0] = qb; pa.C[1] = kb; pa.C[2] = vt;
    pa.ns[0] = Dd; pa.ns[1] = Dd; pa.ns[2] = 1;
    pa.cs[0] = 1;  pa.cs[1] = 1;  pa.cs[2] = Nn;
    pa.scale[0] = 0.125f; pa.scale[1] = 1.0f; pa.scale[2] = 1.0f;
    pa.box = box; pa.mask = mask; pa.Wg = Wg; pa.bg = bg; pa.lw = lwh;
    pre_k<<<dim3(11 * 256), 256, 0, stream>>>(pa);

    // 2) fused attention
    attn_k<<<dim3(Bq * Hh * (Nn / 64)), 256, 0, stream>>>(qb, kb, vt, lwh, ob);

    // 3) output projection
    outproj_k<<<dim3(8, 32), 256, 0, stream>>>(ob, Wo, bo, out);
}